// Round 3
// baseline (3419.164 us; speedup 1.0000x reference)
//
#include <hip/hip_runtime.h>

// ---------- types ----------
typedef short short8 __attribute__((ext_vector_type(8)));
typedef unsigned short ushort8 __attribute__((ext_vector_type(8)));
typedef float float4v __attribute__((ext_vector_type(4)));

// ---------- bf16 helpers (bit-level, no header dependence) ----------
__device__ __forceinline__ unsigned short f2bf(float f) {
    union { float f; unsigned u; } v; v.f = f;
    unsigned r = v.u + 0x7fffu + ((v.u >> 16) & 1u);   // RNE
    return (unsigned short)(r >> 16);
}
__device__ __forceinline__ float bf2f(unsigned short s) {
    union { unsigned u; float f; } v; v.u = ((unsigned)s) << 16;
    return v.f;
}

// ---------- async global->LDS, 16B per lane ----------
__device__ __forceinline__ void async_copy16(const void* g, void* l) {
    __builtin_amdgcn_global_load_lds(
        (__attribute__((address_space(1))) void*)g,
        (__attribute__((address_space(3))) void*)l,
        16, 0, 0);
}

// ---------- fp32 -> bf16 cast (vectorized) ----------
__global__ __launch_bounds__(256) void cast_bf16_kernel(
        const float* __restrict__ in, unsigned short* __restrict__ out, int n) {
    int i4 = (blockIdx.x * 256 + threadIdx.x) * 4;
    if (i4 < n) {
        float4 f = *(const float4*)(in + i4);
        ushort4 u;
        u.x = f2bf(f.x); u.y = f2bf(f.y); u.z = f2bf(f.z); u.w = f2bf(f.w);
        *(ushort4*)(out + i4) = u;
    }
}

// batched small casts: one launch covers up to 8 tensors (grid.y selects)
struct CastBatch {
    const float* src[8];
    unsigned short* dst[8];
    int n[8];
};
__global__ __launch_bounds__(256) void cast_batch_kernel(CastBatch cb) {
    const int t = blockIdx.y;
    const int n = cb.n[t];
    int i4 = (blockIdx.x * 256 + threadIdx.x) * 4;
    if (i4 < n) {
        float4 f = *(const float4*)(cb.src[t] + i4);
        ushort4 u;
        u.x = f2bf(f.x); u.y = f2bf(f.y); u.z = f2bf(f.z); u.w = f2bf(f.w);
        *(ushort4*)(cb.dst[t] + i4) = u;
    }
}

// ---------- bf16 GEMM core, C[m,n] = sum_k A[m,k]*B[n,k]  (both row-major [rows,K]) ----------
// 128x128 tile, 256 threads = 4 waves (2x2), each wave 64x64 via 4x4 MFMA 16x16x32.
// EPI: 0 = fp32 out, 1 = bf16 out, 2 = fp32 out + bias[col] + resid[row*N+col]
template<int EPI>
__device__ __forceinline__ void gemm_core(
        const unsigned short* __restrict__ A,
        const unsigned short* __restrict__ B,
        float* __restrict__ Cf,
        unsigned short* __restrict__ Cb,
        const float* __restrict__ bias,
        const float* __restrict__ resid,
        int Mclamp, int N, int K, int bm, int bn) {
    __shared__ unsigned short As[128 * 32];   // 8 KB, [row][k] row-major
    __shared__ unsigned short Bs[128 * 32];   // 8 KB

    const int tid  = threadIdx.x;
    const int lane = tid & 63;
    const int wave = tid >> 6;
    const int wm   = (wave >> 1) * 64;
    const int wn   = (wave & 1) * 64;
    const int lr   = lane & 15;   // fragment row / C col
    const int lq   = lane >> 4;   // quad

    float4v acc[4][4] = {};

    const int row_s = tid >> 2;
    const int kk    = (tid & 3) * 8;
    int ar0 = bm + row_s;       if (ar0 >= Mclamp) ar0 = Mclamp - 1;
    int ar1 = bm + row_s + 64;  if (ar1 >= Mclamp) ar1 = Mclamp - 1;
    const int br0 = bn + row_s;
    const int br1 = bn + row_s + 64;

    const unsigned short* a0 = A + (size_t)ar0 * K + kk;
    const unsigned short* a1 = A + (size_t)ar1 * K + kk;
    const unsigned short* b0 = B + (size_t)br0 * K + kk;
    const unsigned short* b1 = B + (size_t)br1 * K + kk;

    char* AsD0 = (char*)As + (size_t)tid * 16;
    char* AsD1 = (char*)As + (size_t)(256 + tid) * 16;
    char* BsD0 = (char*)Bs + (size_t)tid * 16;
    char* BsD1 = (char*)Bs + (size_t)(256 + tid) * 16;

    for (int ks = 0; ks < K; ks += 32) {
        async_copy16(a0 + ks, AsD0);
        async_copy16(a1 + ks, AsD1);
        async_copy16(b0 + ks, BsD0);
        async_copy16(b1 + ks, BsD1);
        __syncthreads();

        short8 af[4], bfr[4];
        #pragma unroll
        for (int i = 0; i < 4; ++i)
            af[i] = *(const short8*)(As + (wm + i * 16 + lr) * 32 + lq * 8);
        #pragma unroll
        for (int j = 0; j < 4; ++j)
            bfr[j] = *(const short8*)(Bs + (wn + j * 16 + lr) * 32 + lq * 8);

        #pragma unroll
        for (int i = 0; i < 4; ++i)
            #pragma unroll
            for (int j = 0; j < 4; ++j)
                acc[i][j] = __builtin_amdgcn_mfma_f32_16x16x32_bf16(
                                af[i], bfr[j], acc[i][j], 0, 0, 0);
        __syncthreads();
    }

    // epilogue: C/D layout col=lane&15, row=(lane>>4)*4+reg   [m89-verified]
    #pragma unroll
    for (int i = 0; i < 4; ++i) {
        #pragma unroll
        for (int r = 0; r < 4; ++r) {
            const int row = bm + wm + i * 16 + lq * 4 + r;
            const size_t base = (size_t)row * N;
            #pragma unroll
            for (int j = 0; j < 4; ++j) {
                const int col = bn + wn + j * 16 + lr;
                const float v = acc[i][j][r];
                const size_t idx = base + col;
                if (EPI == 2)      Cf[idx] = v + bias[col] + resid[idx];
                else if (EPI == 1) Cb[idx] = f2bf(v);
                else               Cf[idx] = v;
            }
        }
    }
}

template<int EPI>
__global__ __launch_bounds__(256) void gemm_bt_kernel(
        const unsigned short* __restrict__ A,
        const unsigned short* __restrict__ B,
        float* __restrict__ Cf,
        unsigned short* __restrict__ Cb,
        const float* __restrict__ bias,
        const float* __restrict__ resid,
        int Mclamp, int N, int K) {
    gemm_core<EPI>(A, B, Cf, Cb, bias, resid, Mclamp, N, K,
                   blockIdx.x * 128, blockIdx.y * 128);
}

// all four K/V/iK/iV projections in one launch; blockIdx.z picks the pair
__global__ __launch_bounds__(256) void gemm_kv4_kernel(
        const unsigned short* __restrict__ Aenc,
        const unsigned short* __restrict__ Aid,
        const unsigned short* __restrict__ Wk,
        const unsigned short* __restrict__ Wv,
        const unsigned short* __restrict__ Wik,
        const unsigned short* __restrict__ Wiv,
        float* __restrict__ Kp, float* __restrict__ Vp,
        float* __restrict__ IKp, float* __restrict__ IVp,
        int N, int K) {
    const int z = blockIdx.z;
    const int bm = blockIdx.x * 128;
    const int Mrows  = (z < 2) ? 384 : 128;   // padded output rows
    if (bm >= Mrows) return;
    const int Mclamp = (z < 2) ? 308 : 128;
    const unsigned short* A = (z < 2) ? Aenc : Aid;
    const unsigned short* B = (z == 0) ? Wk : (z == 1) ? Wv : (z == 2) ? Wik : Wiv;
    float* C = (z == 0) ? Kp : (z == 1) ? Vp : (z == 2) ? IKp : IVp;
    gemm_core<0>(A, B, C, nullptr, nullptr, nullptr, Mclamp, N, K,
                 bm, blockIdx.y * 128);
}

// ---------- fused dual attention (cross T=77 + id L=32) ----------
// 4 lanes per query row, 16 dims each: per-thread state q[16]+accC[16]+accI[16]
// = 48 fp32 -> register-resident (round-2 lesson: 192-float/thread version got
// parked in AGPR/scratch at VGPR=112 regardless of launch_bounds).
// Dot: 16 FMA/lane + shfl_xor(1,2) reduce across the 4-lane group.
// Q bf16 [B*S,1280]; Kp/Vp fp32 [384,1280]; IKp/IVp fp32 [128,1280]
// writes combined bf16 [B*S,1280] at col h*64 + sub*16
__global__ __launch_bounds__(256) void attn_kernel(
        const unsigned short* __restrict__ Q,
        const float* __restrict__ Kp, const float* __restrict__ Vp,
        const float* __restrict__ IKp, const float* __restrict__ IVp,
        unsigned short* __restrict__ Cmb) {
    const int b = blockIdx.z;
    const int h = blockIdx.y;
    const int hoff = h * 64;
    const int rowl = threadIdx.x >> 2;          // 0..63 local query row
    const int sub  = threadIdx.x & 3;           // dim chunk
    const int s    = blockIdx.x * 64 + rowl;
    const int doff = sub * 16;

    __shared__ float Kl[77 * 64];
    __shared__ float Vl[77 * 64];
    __shared__ float IKl[32 * 64];
    __shared__ float IVl[32 * 64];

    for (int i = threadIdx.x; i < 77 * 16; i += 256) {
        const int t = i >> 4, c4 = i & 15;
        const size_t src = (size_t)(b * 77 + t) * 1280 + hoff + c4 * 4;
        ((float4*)Kl)[i] = *(const float4*)(Kp + src);
        ((float4*)Vl)[i] = *(const float4*)(Vp + src);
    }
    for (int i = threadIdx.x; i < 32 * 16; i += 256) {
        const int t = i >> 4, c4 = i & 15;
        const size_t src = (size_t)(b * 32 + t) * 1280 + hoff + c4 * 4;
        ((float4*)IKl)[i] = *(const float4*)(IKp + src);
        ((float4*)IVl)[i] = *(const float4*)(IVp + src);
    }
    __syncthreads();

    // load this lane's 16 q dims (bf16 -> fp32)
    float q[16];
    const unsigned short* qp = Q + (size_t)(b * 4096 + s) * 1280 + hoff + doff;
    #pragma unroll
    for (int c = 0; c < 2; ++c) {
        short8 v = *(const short8*)(qp + c * 8);
        #pragma unroll
        for (int j = 0; j < 8; ++j) q[c * 8 + j] = bf2f((unsigned short)v[j]);
    }

    const float scale = 0.125f;   // 1/sqrt(64)

    float accC[16], accI[16];
    #pragma unroll
    for (int d = 0; d < 16; ++d) { accC[d] = 0.f; accI[d] = 0.f; }
    float lC = 0.f, lI = 0.f;

    // cross attention (scores ~N(0,1): no max-subtraction needed)
    #pragma unroll 2
    for (int j = 0; j < 77; ++j) {
        const float* kr = Kl + j * 64 + doff;
        float s0 = 0.f, s1 = 0.f, s2 = 0.f, s3 = 0.f;
        #pragma unroll
        for (int d = 0; d < 16; d += 4) {
            s0 += q[d + 0] * kr[d + 0];
            s1 += q[d + 1] * kr[d + 1];
            s2 += q[d + 2] * kr[d + 2];
            s3 += q[d + 3] * kr[d + 3];
        }
        float t = (s0 + s1) + (s2 + s3);
        t += __shfl_xor(t, 1);
        t += __shfl_xor(t, 2);
        const float p = __expf(t * scale);
        lC += p;
        const float* vr = Vl + j * 64 + doff;
        #pragma unroll
        for (int d = 0; d < 16; ++d) accC[d] += p * vr[d];
    }

    // id attention
    #pragma unroll 2
    for (int j = 0; j < 32; ++j) {
        const float* kr = IKl + j * 64 + doff;
        float s0 = 0.f, s1 = 0.f, s2 = 0.f, s3 = 0.f;
        #pragma unroll
        for (int d = 0; d < 16; d += 4) {
            s0 += q[d + 0] * kr[d + 0];
            s1 += q[d + 1] * kr[d + 1];
            s2 += q[d + 2] * kr[d + 2];
            s3 += q[d + 3] * kr[d + 3];
        }
        float t = (s0 + s1) + (s2 + s3);
        t += __shfl_xor(t, 1);
        t += __shfl_xor(t, 2);
        const float p = __expf(t * scale);
        lI += p;
        const float* vr = IVl + j * 64 + doff;
        #pragma unroll
        for (int d = 0; d < 16; ++d) accI[d] += p * vr[d];
    }

    const float rC = 1.f / lC;
    const float rI = 1.f / lI;

    unsigned short* op = Cmb + (size_t)(b * 4096 + s) * 1280 + hoff + doff;
    #pragma unroll
    for (int c = 0; c < 2; ++c) {
        ushort8 u;
        #pragma unroll
        for (int j = 0; j < 8; ++j) {
            const int d = c * 8 + j;
            u[j] = f2bf(accC[d] * rC + accI[d] * rI);
        }
        *(ushort8*)(op + c * 8) = u;
    }
}

// ---------- host launch ----------
extern "C" void kernel_launch(void* const* d_in, const int* in_sizes, int n_in,
                              void* d_out, int out_size, void* d_ws, size_t ws_size,
                              hipStream_t stream) {
    const float* hs  = (const float*)d_in[0];   // [4,4096,1280]
    const float* enc = (const float*)d_in[1];   // [4,77,2048]
    const float* idm = (const float*)d_in[2];   // [4,32,2048]
    const float* Wq  = (const float*)d_in[3];   // [1280,1280]
    const float* Wk  = (const float*)d_in[4];   // [1280,2048]
    const float* Wv  = (const float*)d_in[5];
    const float* Wik = (const float*)d_in[6];
    const float* Wiv = (const float*)d_in[7];
    const float* Wo  = (const float*)d_in[8];   // [1280,1280]
    const float* bo  = (const float*)d_in[9];   // [1280]
    float* out = (float*)d_out;

    char* ws = (char*)d_ws;
    size_t off = 0;
    auto carve = [&](size_t bytes) {
        char* p = ws + off;
        off += (bytes + 255) & ~(size_t)255;
        return p;
    };

    unsigned short* Xh   = (unsigned short*)carve(16384ULL * 1280 * 2); // also 'combined'
    unsigned short* Wq_b = (unsigned short*)carve(1280ULL * 1280 * 2);
    unsigned short* Wk_b = (unsigned short*)carve(1280ULL * 2048 * 2);
    unsigned short* Wv_b = (unsigned short*)carve(1280ULL * 2048 * 2);
    unsigned short* Wik_b= (unsigned short*)carve(1280ULL * 2048 * 2);
    unsigned short* Wiv_b= (unsigned short*)carve(1280ULL * 2048 * 2);
    unsigned short* Wo_b = (unsigned short*)carve(1280ULL * 1280 * 2);
    unsigned short* Encb = (unsigned short*)carve(308ULL * 2048 * 2);
    unsigned short* Idb  = (unsigned short*)carve(128ULL * 2048 * 2);
    unsigned short* Qb   = (unsigned short*)carve(16384ULL * 1280 * 2);
    float* Kp  = (float*)carve(384ULL * 1280 * 4);
    float* Vp  = (float*)carve(384ULL * 1280 * 4);
    float* IKp = (float*)carve(128ULL * 1280 * 4);
    float* IVp = (float*)carve(128ULL * 1280 * 4);
    (void)ws_size; (void)in_sizes; (void)n_in; (void)out_size;

    // big cast (hidden_states)
    cast_bf16_kernel<<<(4 * 4096 * 1280 / 4 + 255) / 256, 256, 0, stream>>>(
        hs, Xh, 4 * 4096 * 1280);

    // batched small casts (8 tensors, one launch)
    CastBatch cb;
    cb.src[0] = Wq;  cb.dst[0] = Wq_b;  cb.n[0] = 1280 * 1280;
    cb.src[1] = Wk;  cb.dst[1] = Wk_b;  cb.n[1] = 1280 * 2048;
    cb.src[2] = Wv;  cb.dst[2] = Wv_b;  cb.n[2] = 1280 * 2048;
    cb.src[3] = Wik; cb.dst[3] = Wik_b; cb.n[3] = 1280 * 2048;
    cb.src[4] = Wiv; cb.dst[4] = Wiv_b; cb.n[4] = 1280 * 2048;
    cb.src[5] = Wo;  cb.dst[5] = Wo_b;  cb.n[5] = 1280 * 1280;
    cb.src[6] = enc; cb.dst[6] = Encb;  cb.n[6] = 4 * 77 * 2048;
    cb.src[7] = idm; cb.dst[7] = Idb;   cb.n[7] = 4 * 32 * 2048;
    cast_batch_kernel<<<dim3((1280 * 2048 / 4 + 255) / 256, 8), 256, 0, stream>>>(cb);

    // Q = hs @ Wq^T   -> bf16 [16384,1280]
    gemm_bt_kernel<1><<<dim3(128, 10), 256, 0, stream>>>(
        Xh, Wq_b, nullptr, Qb, nullptr, nullptr, 16384, 1280, 1280);

    // all 4 K/V projections in one launch (z=0..3)
    gemm_kv4_kernel<<<dim3(3, 10, 4), 256, 0, stream>>>(
        Encb, Idb, Wk_b, Wv_b, Wik_b, Wiv_b, Kp, Vp, IKp, IVp, 1280, 2048);

    // fused cross+id attention -> combined (reuses Xh buffer)
    attn_kernel<<<dim3(64, 20, 4), 256, 0, stream>>>(Qb, Kp, Vp, IKp, IVp, Xh);

    // out = combined @ Wo^T + bo + residual(hs)   -> fp32 d_out
    gemm_bt_kernel<2><<<dim3(128, 10), 256, 0, stream>>>(
        Xh, Wo_b, out, nullptr, bo, hs, 16384, 1280, 1280);
}

// Round 4
// 491.147 us; speedup vs baseline: 6.9616x; 6.9616x over previous
//
#include <hip/hip_runtime.h>

// ---------- types ----------
typedef short short8 __attribute__((ext_vector_type(8)));
typedef unsigned short ushort8 __attribute__((ext_vector_type(8)));
typedef float float4v __attribute__((ext_vector_type(4)));

// ---------- bf16 helpers (bit-level) ----------
__device__ __forceinline__ unsigned short f2bf(float f) {
    union { float f; unsigned u; } v; v.f = f;
    unsigned r = v.u + 0x7fffu + ((v.u >> 16) & 1u);   // RNE
    return (unsigned short)(r >> 16);
}

// ---------- async global->LDS, 16B per lane ----------
__device__ __forceinline__ void async_copy16(const void* g, void* l) {
    __builtin_amdgcn_global_load_lds(
        (__attribute__((address_space(1))) void*)g,
        (__attribute__((address_space(3))) void*)l,
        16, 0, 0);
}

// ---------- fp32 -> bf16 cast (vectorized) ----------
__global__ __launch_bounds__(256) void cast_bf16_kernel(
        const float* __restrict__ in, unsigned short* __restrict__ out, int n) {
    int i4 = (blockIdx.x * 256 + threadIdx.x) * 4;
    if (i4 < n) {
        float4 f = *(const float4*)(in + i4);
        ushort4 u;
        u.x = f2bf(f.x); u.y = f2bf(f.y); u.z = f2bf(f.z); u.w = f2bf(f.w);
        *(ushort4*)(out + i4) = u;
    }
}

// encoder cast with per-batch row padding 77 -> 96  ([4,77,2048] -> [4,96,2048])
__global__ __launch_bounds__(256) void cast_enc_pad_kernel(
        const float* __restrict__ in, unsigned short* __restrict__ out) {
    int i4 = blockIdx.x * 256 + threadIdx.x;         // float4 index
    if (i4 < 4 * 77 * 2048 / 4) {
        const int per_b = 77 * 2048 / 4;             // 39424
        int b = i4 / per_b;
        int rem = i4 - b * per_b;
        float4 f = *(const float4*)(in + (size_t)i4 * 4);
        ushort4 u;
        u.x = f2bf(f.x); u.y = f2bf(f.y); u.z = f2bf(f.z); u.w = f2bf(f.w);
        *(ushort4*)(out + ((size_t)b * (96 * 2048 / 4) + rem) * 4) = u;
    }
}

// batched small casts (grid.y selects tensor)
struct CastBatch {
    const float* src[8];
    unsigned short* dst[8];
    int n[8];
};
__global__ __launch_bounds__(256) void cast_batch_kernel(CastBatch cb) {
    const int t = blockIdx.y;
    const int n = cb.n[t];
    int i4 = (blockIdx.x * 256 + threadIdx.x) * 4;
    if (i4 < n) {
        float4 f = *(const float4*)(cb.src[t] + i4);
        ushort4 u;
        u.x = f2bf(f.x); u.y = f2bf(f.y); u.z = f2bf(f.z); u.w = f2bf(f.w);
        *(ushort4*)(cb.dst[t] + i4) = u;
    }
}

// ---------- bf16 GEMM core, C[m,n] = sum_k A[m,k]*B[n,k] ----------
// EPI: 0 = fp32 out, 1 = bf16 out, 2 = fp32 out + bias[col] + resid[row*N+col]
template<int EPI>
__device__ __forceinline__ void gemm_core(
        const unsigned short* __restrict__ A,
        const unsigned short* __restrict__ B,
        float* __restrict__ Cf,
        unsigned short* __restrict__ Cb,
        const float* __restrict__ bias,
        const float* __restrict__ resid,
        int Mclamp, int N, int K, int bm, int bn) {
    __shared__ unsigned short As[128 * 32];
    __shared__ unsigned short Bs[128 * 32];

    const int tid  = threadIdx.x;
    const int lane = tid & 63;
    const int wave = tid >> 6;
    const int wm   = (wave >> 1) * 64;
    const int wn   = (wave & 1) * 64;
    const int lr   = lane & 15;
    const int lq   = lane >> 4;

    float4v acc[4][4] = {};

    const int row_s = tid >> 2;
    const int kk    = (tid & 3) * 8;
    int ar0 = bm + row_s;       if (ar0 >= Mclamp) ar0 = Mclamp - 1;
    int ar1 = bm + row_s + 64;  if (ar1 >= Mclamp) ar1 = Mclamp - 1;
    const int br0 = bn + row_s;
    const int br1 = bn + row_s + 64;

    const unsigned short* a0 = A + (size_t)ar0 * K + kk;
    const unsigned short* a1 = A + (size_t)ar1 * K + kk;
    const unsigned short* b0 = B + (size_t)br0 * K + kk;
    const unsigned short* b1 = B + (size_t)br1 * K + kk;

    char* AsD0 = (char*)As + (size_t)tid * 16;
    char* AsD1 = (char*)As + (size_t)(256 + tid) * 16;
    char* BsD0 = (char*)Bs + (size_t)tid * 16;
    char* BsD1 = (char*)Bs + (size_t)(256 + tid) * 16;

    for (int ks = 0; ks < K; ks += 32) {
        async_copy16(a0 + ks, AsD0);
        async_copy16(a1 + ks, AsD1);
        async_copy16(b0 + ks, BsD0);
        async_copy16(b1 + ks, BsD1);
        __syncthreads();

        short8 af[4], bfr[4];
        #pragma unroll
        for (int i = 0; i < 4; ++i)
            af[i] = *(const short8*)(As + (wm + i * 16 + lr) * 32 + lq * 8);
        #pragma unroll
        for (int j = 0; j < 4; ++j)
            bfr[j] = *(const short8*)(Bs + (wn + j * 16 + lr) * 32 + lq * 8);

        #pragma unroll
        for (int i = 0; i < 4; ++i)
            #pragma unroll
            for (int j = 0; j < 4; ++j)
                acc[i][j] = __builtin_amdgcn_mfma_f32_16x16x32_bf16(
                                af[i], bfr[j], acc[i][j], 0, 0, 0);
        __syncthreads();
    }

    // C/D layout: col=lane&15, row=(lane>>4)*4+reg   [m89-verified]
    #pragma unroll
    for (int i = 0; i < 4; ++i) {
        #pragma unroll
        for (int r = 0; r < 4; ++r) {
            const int row = bm + wm + i * 16 + lq * 4 + r;
            const size_t base = (size_t)row * N;
            #pragma unroll
            for (int j = 0; j < 4; ++j) {
                const int col = bn + wn + j * 16 + lr;
                const float v = acc[i][j][r];
                const size_t idx = base + col;
                if (EPI == 2)      Cf[idx] = v + bias[col] + resid[idx];
                else if (EPI == 1) Cb[idx] = f2bf(v);
                else               Cf[idx] = v;
            }
        }
    }
}

template<int EPI>
__global__ __launch_bounds__(256) void gemm_bt_kernel(
        const unsigned short* __restrict__ A,
        const unsigned short* __restrict__ B,
        float* __restrict__ Cf,
        unsigned short* __restrict__ Cb,
        const float* __restrict__ bias,
        const float* __restrict__ resid,
        int Mclamp, int N, int K) {
    gemm_core<EPI>(A, B, Cf, Cb, bias, resid, Mclamp, N, K,
                   blockIdx.x * 128, blockIdx.y * 128);
}

// all four K/V/iK/iV projections in one launch -> bf16 outputs
__global__ __launch_bounds__(256) void gemm_kv4_kernel(
        const unsigned short* __restrict__ Aenc,   // [384,2048] per-batch padded
        const unsigned short* __restrict__ Aid,    // [128,2048]
        const unsigned short* __restrict__ Wk,
        const unsigned short* __restrict__ Wv,
        const unsigned short* __restrict__ Wik,
        const unsigned short* __restrict__ Wiv,
        unsigned short* __restrict__ Kb, unsigned short* __restrict__ Vb,
        unsigned short* __restrict__ IKb, unsigned short* __restrict__ IVb,
        int N, int K) {
    const int z = blockIdx.z;
    const int bm = blockIdx.x * 128;
    const int Mrows = (z < 2) ? 384 : 128;
    if (bm >= Mrows) return;
    const unsigned short* A = (z < 2) ? Aenc : Aid;
    const unsigned short* B = (z == 0) ? Wk : (z == 1) ? Wv : (z == 2) ? Wik : Wiv;
    unsigned short* C = (z == 0) ? Kb : (z == 1) ? Vb : (z == 2) ? IKb : IVb;
    gemm_core<1>(A, B, nullptr, C, nullptr, nullptr, Mrows, N, K,
                 bm, blockIdx.y * 128);
}

// ---------- MFMA fused dual attention ----------
// Block = 64 Q-rows x one (b,h); 4 waves x 16 Q-rows each.
// Scores: mfma_16x16x32_bf16, A=Q rows (global), B=K rows (global bf16).
// Cross keys padded 77->80 scored (5 tiles, n>=77 masked), PV over 96 keys
// (P cols 80..95 zeroed). Id keys = 32 exact (P cols 96..127).
// V staged transposed in LDS: Vt[d][key], stride 136 shorts (bank-safe, 16B-aligned).
// P round-trips through LDS (C-layout -> A-layout). Accumulators are MFMA
// C/D fragments => AGPR-resident by construction (R1/R3 lesson: scalar fp32
// accumulator arrays spill).
#define VT_STRIDE 136
__global__ __launch_bounds__(256) void attn_mfma_kernel(
        const unsigned short* __restrict__ Q,     // [16384,1280] bf16
        const unsigned short* __restrict__ Kb,    // [384,1280]  bf16, rows b*96+t
        const unsigned short* __restrict__ Vb,    // [384,1280]  bf16
        const unsigned short* __restrict__ IKb,   // [128,1280]  bf16, rows b*32+t
        const unsigned short* __restrict__ IVb,   // [128,1280]  bf16
        unsigned short* __restrict__ Cmb) {       // [16384,1280] bf16
    const int b = blockIdx.z;
    const int h = blockIdx.y;
    const int hoff = h * 64;
    const int qbase = blockIdx.x * 64;
    const int tid = threadIdx.x;
    const int lane = tid & 63;
    const int wave = tid >> 6;
    const int l15 = lane & 15;
    const int quad = lane >> 4;

    __shared__ unsigned short Vt[64 * VT_STRIDE];  // [d][key] cross 0..95, id 96..127
    __shared__ unsigned short Pl[64 * VT_STRIDE];  // [qrow][key] same col map

    // ---- stage V transposed (cross): 96 keys x 8 chunks of 8 d ----
    for (int i = tid; i < 96 * 8; i += 256) {
        const int c = i / 96;            // d-chunk 0..7
        const int key = i - c * 96;      // 0..95 (consecutive lanes -> consecutive keys)
        short8 v = *(const short8*)(Vb + (size_t)(b * 96 + key) * 1280 + hoff + c * 8);
        #pragma unroll
        for (int j = 0; j < 8; ++j)
            Vt[(c * 8 + j) * VT_STRIDE + key] = (unsigned short)v[j];
    }
    // ---- stage iV transposed: 32 keys x 8 chunks ----
    {
        const int c = tid >> 5;          // 0..7
        const int key = tid & 31;
        short8 v = *(const short8*)(IVb + (size_t)(b * 32 + key) * 1280 + hoff + c * 8);
        #pragma unroll
        for (int j = 0; j < 8; ++j)
            Vt[(c * 8 + j) * VT_STRIDE + 96 + key] = (unsigned short)v[j];
    }
    __syncthreads();

    // ---- Q A-fragments (direct from global; reused across all score tiles) ----
    const int qrow = b * 4096 + qbase + wave * 16 + l15;
    const unsigned short* qp = Q + (size_t)qrow * 1280 + hoff + quad * 8;
    const short8 aQ0 = *(const short8*)(qp);
    const short8 aQ1 = *(const short8*)(qp + 32);

    const float scale = 0.125f;
    float lC[4] = {0.f, 0.f, 0.f, 0.f};
    float lI[4] = {0.f, 0.f, 0.f, 0.f};

    // ---- cross scores: 5 n-tiles (keys 0..79) ----
    #pragma unroll
    for (int t = 0; t < 5; ++t) {
        const unsigned short* kp = Kb + (size_t)(b * 96 + t * 16 + l15) * 1280 + hoff + quad * 8;
        const short8 bK0 = *(const short8*)(kp);
        const short8 bK1 = *(const short8*)(kp + 32);
        float4v s = {};
        s = __builtin_amdgcn_mfma_f32_16x16x32_bf16(aQ0, bK0, s, 0, 0, 0);
        s = __builtin_amdgcn_mfma_f32_16x16x32_bf16(aQ1, bK1, s, 0, 0, 0);
        #pragma unroll
        for (int r = 0; r < 4; ++r) {
            float p = __expf(s[r] * scale);
            if (t == 4 && l15 >= 13) p = 0.f;   // keys 77..79 masked
            lC[r] += p;
            Pl[(wave * 16 + quad * 4 + r) * VT_STRIDE + t * 16 + l15] = f2bf(p);
        }
    }
    // zero P cols 80..95 (PV runs K=96)
    #pragma unroll
    for (int r = 0; r < 4; ++r)
        Pl[(wave * 16 + quad * 4 + r) * VT_STRIDE + 80 + l15] = 0;

    // ---- id scores: 2 n-tiles (keys 0..31 -> P cols 96..127) ----
    #pragma unroll
    for (int t = 0; t < 2; ++t) {
        const unsigned short* kp = IKb + (size_t)(b * 32 + t * 16 + l15) * 1280 + hoff + quad * 8;
        const short8 bK0 = *(const short8*)(kp);
        const short8 bK1 = *(const short8*)(kp + 32);
        float4v s = {};
        s = __builtin_amdgcn_mfma_f32_16x16x32_bf16(aQ0, bK0, s, 0, 0, 0);
        s = __builtin_amdgcn_mfma_f32_16x16x32_bf16(aQ1, bK1, s, 0, 0, 0);
        #pragma unroll
        for (int r = 0; r < 4; ++r) {
            const float p = __expf(s[r] * scale);
            lI[r] += p;
            Pl[(wave * 16 + quad * 4 + r) * VT_STRIDE + 96 + t * 16 + l15] = f2bf(p);
        }
    }

    // ---- row sums: reduce across the 16 lanes of each quad ----
    #pragma unroll
    for (int m = 1; m <= 8; m <<= 1) {
        #pragma unroll
        for (int r = 0; r < 4; ++r) {
            lC[r] += __shfl_xor(lC[r], m);
            lI[r] += __shfl_xor(lI[r], m);
        }
    }
    __syncthreads();   // P complete (paranoia: same-wave rows, but cheap)

    // ---- PV: O[m][d] = sum_key P[m,key] * Vt[d][key] ----
    float4v oC[4] = {};
    float4v oI[4] = {};
    #pragma unroll
    for (int kt = 0; kt < 3; ++kt) {
        const short8 aP = *(const short8*)(Pl + (wave * 16 + l15) * VT_STRIDE + kt * 32 + quad * 8);
        #pragma unroll
        for (int td = 0; td < 4; ++td) {
            const short8 bV = *(const short8*)(Vt + (td * 16 + l15) * VT_STRIDE + kt * 32 + quad * 8);
            oC[td] = __builtin_amdgcn_mfma_f32_16x16x32_bf16(aP, bV, oC[td], 0, 0, 0);
        }
    }
    {
        const short8 aP = *(const short8*)(Pl + (wave * 16 + l15) * VT_STRIDE + 96 + quad * 8);
        #pragma unroll
        for (int td = 0; td < 4; ++td) {
            const short8 bV = *(const short8*)(Vt + (td * 16 + l15) * VT_STRIDE + 96 + quad * 8);
            oI[td] = __builtin_amdgcn_mfma_f32_16x16x32_bf16(aP, bV, oI[td], 0, 0, 0);
        }
    }

    // ---- normalize + combine + store ----
    float rc[4], ri[4];
    #pragma unroll
    for (int r = 0; r < 4; ++r) { rc[r] = 1.f / lC[r]; ri[r] = 1.f / lI[r]; }

    #pragma unroll
    for (int td = 0; td < 4; ++td) {
        #pragma unroll
        for (int r = 0; r < 4; ++r) {
            const int row = b * 4096 + qbase + wave * 16 + quad * 4 + r;
            const int col = hoff + td * 16 + l15;
            Cmb[(size_t)row * 1280 + col] = f2bf(oC[td][r] * rc[r] + oI[td][r] * ri[r]);
        }
    }
}

// ---------- host launch ----------
extern "C" void kernel_launch(void* const* d_in, const int* in_sizes, int n_in,
                              void* d_out, int out_size, void* d_ws, size_t ws_size,
                              hipStream_t stream) {
    const float* hs  = (const float*)d_in[0];   // [4,4096,1280]
    const float* enc = (const float*)d_in[1];   // [4,77,2048]
    const float* idm = (const float*)d_in[2];   // [4,32,2048]
    const float* Wq  = (const float*)d_in[3];
    const float* Wk  = (const float*)d_in[4];
    const float* Wv  = (const float*)d_in[5];
    const float* Wik = (const float*)d_in[6];
    const float* Wiv = (const float*)d_in[7];
    const float* Wo  = (const float*)d_in[8];
    const float* bo  = (const float*)d_in[9];
    float* out = (float*)d_out;

    char* ws = (char*)d_ws;
    size_t off = 0;
    auto carve = [&](size_t bytes) {
        char* p = ws + off;
        off += (bytes + 255) & ~(size_t)255;
        return p;
    };

    unsigned short* Xh   = (unsigned short*)carve(16384ULL * 1280 * 2); // hs bf16, later 'combined'
    unsigned short* Wq_b = (unsigned short*)carve(1280ULL * 1280 * 2);
    unsigned short* Wk_b = (unsigned short*)carve(1280ULL * 2048 * 2);
    unsigned short* Wv_b = (unsigned short*)carve(1280ULL * 2048 * 2);
    unsigned short* Wik_b= (unsigned short*)carve(1280ULL * 2048 * 2);
    unsigned short* Wiv_b= (unsigned short*)carve(1280ULL * 2048 * 2);
    unsigned short* Wo_b = (unsigned short*)carve(1280ULL * 1280 * 2);
    unsigned short* Encb = (unsigned short*)carve(384ULL * 2048 * 2);  // per-batch padded 96 rows
    unsigned short* Idb  = (unsigned short*)carve(128ULL * 2048 * 2);
    unsigned short* Qb   = (unsigned short*)carve(16384ULL * 1280 * 2);
    unsigned short* Kb   = (unsigned short*)carve(384ULL * 1280 * 2);
    unsigned short* Vb   = (unsigned short*)carve(384ULL * 1280 * 2);
    unsigned short* IKb  = (unsigned short*)carve(128ULL * 1280 * 2);
    unsigned short* IVb  = (unsigned short*)carve(128ULL * 1280 * 2);
    (void)ws_size; (void)in_sizes; (void)n_in; (void)out_size;

    // hidden_states cast
    cast_bf16_kernel<<<(4 * 4096 * 1280 / 4 + 255) / 256, 256, 0, stream>>>(
        hs, Xh, 4 * 4096 * 1280);
    // encoder cast with per-batch padding
    cast_enc_pad_kernel<<<(4 * 77 * 2048 / 4 + 255) / 256, 256, 0, stream>>>(enc, Encb);

    // batched small casts (7 tensors)
    CastBatch cb;
    cb.src[0] = Wq;  cb.dst[0] = Wq_b;  cb.n[0] = 1280 * 1280;
    cb.src[1] = Wk;  cb.dst[1] = Wk_b;  cb.n[1] = 1280 * 2048;
    cb.src[2] = Wv;  cb.dst[2] = Wv_b;  cb.n[2] = 1280 * 2048;
    cb.src[3] = Wik; cb.dst[3] = Wik_b; cb.n[3] = 1280 * 2048;
    cb.src[4] = Wiv; cb.dst[4] = Wiv_b; cb.n[4] = 1280 * 2048;
    cb.src[5] = Wo;  cb.dst[5] = Wo_b;  cb.n[5] = 1280 * 1280;
    cb.src[6] = idm; cb.dst[6] = Idb;   cb.n[6] = 4 * 32 * 2048;
    cb.src[7] = nullptr; cb.dst[7] = nullptr; cb.n[7] = 0;
    cast_batch_kernel<<<dim3((1280 * 2048 / 4 + 255) / 256, 7), 256, 0, stream>>>(cb);

    // Q = hs @ Wq^T -> bf16
    gemm_bt_kernel<1><<<dim3(128, 10), 256, 0, stream>>>(
        Xh, Wq_b, nullptr, Qb, nullptr, nullptr, 16384, 1280, 1280);

    // K/V/iK/iV projections -> bf16 (z=0..3)
    gemm_kv4_kernel<<<dim3(3, 10, 4), 256, 0, stream>>>(
        Encb, Idb, Wk_b, Wv_b, Wik_b, Wiv_b, Kb, Vb, IKb, IVb, 1280, 2048);

    // fused MFMA attention -> combined (reuses Xh)
    attn_mfma_kernel<<<dim3(64, 20, 4), 256, 0, stream>>>(Qb, Kb, Vb, IKb, IVb, Xh);

    // out = combined @ Wo^T + bo + residual
    gemm_bt_kernel<2><<<dim3(128, 10), 256, 0, stream>>>(
        Xh, Wo_b, out, nullptr, bo, hs, 16384, 1280, 1280);
}

// Round 5
// 478.326 us; speedup vs baseline: 7.1482x; 1.0268x over previous
//
#include <hip/hip_runtime.h>

// ---------- types ----------
typedef short short8 __attribute__((ext_vector_type(8)));
typedef unsigned short ushort8 __attribute__((ext_vector_type(8)));
typedef float float4v __attribute__((ext_vector_type(4)));

// ---------- bf16 helpers (bit-level) ----------
__device__ __forceinline__ unsigned short f2bf(float f) {
    union { float f; unsigned u; } v; v.f = f;
    unsigned r = v.u + 0x7fffu + ((v.u >> 16) & 1u);   // RNE
    return (unsigned short)(r >> 16);
}

// ---------- async global->LDS, 16B per lane ----------
__device__ __forceinline__ void async_copy16(const void* g, void* l) {
    __builtin_amdgcn_global_load_lds(
        (__attribute__((address_space(1))) void*)g,
        (__attribute__((address_space(3))) void*)l,
        16, 0, 0);
}

// ---------- fp32 -> bf16 cast (vectorized) ----------
__global__ __launch_bounds__(256) void cast_bf16_kernel(
        const float* __restrict__ in, unsigned short* __restrict__ out, int n) {
    int i4 = (blockIdx.x * 256 + threadIdx.x) * 4;
    if (i4 < n) {
        float4 f = *(const float4*)(in + i4);
        ushort4 u;
        u.x = f2bf(f.x); u.y = f2bf(f.y); u.z = f2bf(f.z); u.w = f2bf(f.w);
        *(ushort4*)(out + i4) = u;
    }
}

// encoder cast with per-batch row padding 77 -> 96  ([4,77,2048] -> [4,96,2048])
__global__ __launch_bounds__(256) void cast_enc_pad_kernel(
        const float* __restrict__ in, unsigned short* __restrict__ out) {
    int i4 = blockIdx.x * 256 + threadIdx.x;         // float4 index
    if (i4 < 4 * 77 * 2048 / 4) {
        const int per_b = 77 * 2048 / 4;             // 39424
        int b = i4 / per_b;
        int rem = i4 - b * per_b;
        float4 f = *(const float4*)(in + (size_t)i4 * 4);
        ushort4 u;
        u.x = f2bf(f.x); u.y = f2bf(f.y); u.z = f2bf(f.z); u.w = f2bf(f.w);
        *(ushort4*)(out + ((size_t)b * (96 * 2048 / 4) + rem) * 4) = u;
    }
}

// batched small casts (grid.y selects tensor)
struct CastBatch {
    const float* src[8];
    unsigned short* dst[8];
    int n[8];
};
__global__ __launch_bounds__(256) void cast_batch_kernel(CastBatch cb) {
    const int t = blockIdx.y;
    const int n = cb.n[t];
    int i4 = (blockIdx.x * 256 + threadIdx.x) * 4;
    if (i4 < n) {
        float4 f = *(const float4*)(cb.src[t] + i4);
        ushort4 u;
        u.x = f2bf(f.x); u.y = f2bf(f.y); u.z = f2bf(f.z); u.w = f2bf(f.w);
        *(ushort4*)(cb.dst[t] + i4) = u;
    }
}

// ---------- bf16 GEMM core, C[m,n] = sum_k A[m,k]*B[n,k] ----------
// 128x128 tile, BK=64 (32 MFMA/barrier/wave — 2x barrier amortization vs BK=32).
// LDS rows are 128B (bank-aligned) so chunks are XOR-swizzled: physical chunk p
// of row r holds logical chunk p^(r&7). Source address permuted at staging
// (LDS dest must stay tid*16: global_load_lds is wave-uniform-base + lane*16);
// reads apply the same XOR -> 16 consecutive-row lanes cover all eight 16B
// positions twice = 2-way = free (m136). R4 evidence: 64B-stride layout gave
// 6.55M SQ_LDS_BANK_CONFLICT (~8-way).
// EPI: 0 = fp32 out, 1 = bf16 out, 2 = fp32 out + bias[col] + resid[row*N+col]
template<int EPI>
__device__ __forceinline__ void gemm_core(
        const unsigned short* __restrict__ A,
        const unsigned short* __restrict__ B,
        float* __restrict__ Cf,
        unsigned short* __restrict__ Cb,
        const float* __restrict__ bias,
        const float* __restrict__ resid,
        int Mclamp, int N, int K, int bm, int bn) {
    __shared__ unsigned short As[128 * 64];   // 16 KB
    __shared__ unsigned short Bs[128 * 64];   // 16 KB

    const int tid  = threadIdx.x;
    const int lane = tid & 63;
    const int wave = tid >> 6;
    const int wm   = (wave >> 1) * 64;
    const int wn   = (wave & 1) * 64;
    const int lr   = lane & 15;
    const int lq   = lane >> 4;

    float4v acc[4][4] = {};

    // staging: round r, slot linear = r*256+tid -> row = linear>>3, phys chunk = linear&7
    // source logical chunk = phys ^ (row&7)
    const unsigned short* aptr[4];
    const unsigned short* bptr[4];
    #pragma unroll
    for (int r = 0; r < 4; ++r) {
        const int linear = r * 256 + tid;
        const int row = linear >> 3;
        const int c = (linear & 7) ^ (row & 7);
        int ar = bm + row; if (ar >= Mclamp) ar = Mclamp - 1;
        aptr[r] = A + (size_t)ar * K + c * 8;
        bptr[r] = B + (size_t)(bn + row) * K + c * 8;
    }

    for (int ks = 0; ks < K; ks += 64) {
        #pragma unroll
        for (int r = 0; r < 4; ++r) {
            async_copy16(aptr[r] + ks, (char*)As + (size_t)(r * 256 + tid) * 16);
            async_copy16(bptr[r] + ks, (char*)Bs + (size_t)(r * 256 + tid) * 16);
        }
        __syncthreads();

        #pragma unroll
        for (int kw = 0; kw < 2; ++kw) {
            short8 af[4], bfr[4];
            #pragma unroll
            for (int i = 0; i < 4; ++i) {
                const int row = wm + i * 16 + lr;
                af[i] = *(const short8*)(As + row * 64 + (((kw << 2) | lq) ^ (row & 7)) * 8);
            }
            #pragma unroll
            for (int j = 0; j < 4; ++j) {
                const int row = wn + j * 16 + lr;
                bfr[j] = *(const short8*)(Bs + row * 64 + (((kw << 2) | lq) ^ (row & 7)) * 8);
            }
            #pragma unroll
            for (int i = 0; i < 4; ++i)
                #pragma unroll
                for (int j = 0; j < 4; ++j)
                    acc[i][j] = __builtin_amdgcn_mfma_f32_16x16x32_bf16(
                                    af[i], bfr[j], acc[i][j], 0, 0, 0);
        }
        __syncthreads();
    }

    // C/D layout: col=lane&15, row=(lane>>4)*4+reg   [m89-verified]
    #pragma unroll
    for (int i = 0; i < 4; ++i) {
        #pragma unroll
        for (int r = 0; r < 4; ++r) {
            const int row = bm + wm + i * 16 + lq * 4 + r;
            const size_t base = (size_t)row * N;
            #pragma unroll
            for (int j = 0; j < 4; ++j) {
                const int col = bn + wn + j * 16 + lr;
                const float v = acc[i][j][r];
                const size_t idx = base + col;
                if (EPI == 2)      Cf[idx] = v + bias[col] + resid[idx];
                else if (EPI == 1) Cb[idx] = f2bf(v);
                else               Cf[idx] = v;
            }
        }
    }
}

template<int EPI>
__global__ __launch_bounds__(256) void gemm_bt_kernel(
        const unsigned short* __restrict__ A,
        const unsigned short* __restrict__ B,
        float* __restrict__ Cf,
        unsigned short* __restrict__ Cb,
        const float* __restrict__ bias,
        const float* __restrict__ resid,
        int Mclamp, int N, int K) {
    gemm_core<EPI>(A, B, Cf, Cb, bias, resid, Mclamp, N, K,
                   blockIdx.x * 128, blockIdx.y * 128);
}

// all four K/V/iK/iV projections in one launch -> bf16 outputs
__global__ __launch_bounds__(256) void gemm_kv4_kernel(
        const unsigned short* __restrict__ Aenc,   // [384,2048] per-batch padded
        const unsigned short* __restrict__ Aid,    // [128,2048]
        const unsigned short* __restrict__ Wk,
        const unsigned short* __restrict__ Wv,
        const unsigned short* __restrict__ Wik,
        const unsigned short* __restrict__ Wiv,
        unsigned short* __restrict__ Kb, unsigned short* __restrict__ Vb,
        unsigned short* __restrict__ IKb, unsigned short* __restrict__ IVb,
        int N, int K) {
    const int z = blockIdx.z;
    const int bm = blockIdx.x * 128;
    const int Mrows = (z < 2) ? 384 : 128;
    if (bm >= Mrows) return;
    const unsigned short* A = (z < 2) ? Aenc : Aid;
    const unsigned short* B = (z == 0) ? Wk : (z == 1) ? Wv : (z == 2) ? Wik : Wiv;
    unsigned short* C = (z == 0) ? Kb : (z == 1) ? Vb : (z == 2) ? IKb : IVb;
    gemm_core<1>(A, B, nullptr, C, nullptr, nullptr, Mrows, N, K,
                 bm, blockIdx.y * 128);
}

// ---------- MFMA fused dual attention ----------
// Block = 64 Q-rows x one (b,h); 4 waves x 16 Q-rows each.
// Accumulators are MFMA C/D fragments => AGPR-resident (R1/R3 lesson: scalar
// fp32 accumulator arrays spill to AGPR-shuffles or scratch).
#define VT_STRIDE 136
__global__ __launch_bounds__(256) void attn_mfma_kernel(
        const unsigned short* __restrict__ Q,     // [16384,1280] bf16
        const unsigned short* __restrict__ Kb,    // [384,1280]  bf16, rows b*96+t
        const unsigned short* __restrict__ Vb,    // [384,1280]  bf16
        const unsigned short* __restrict__ IKb,   // [128,1280]  bf16, rows b*32+t
        const unsigned short* __restrict__ IVb,   // [128,1280]  bf16
        unsigned short* __restrict__ Cmb) {       // [16384,1280] bf16
    const int b = blockIdx.z;
    const int h = blockIdx.y;
    const int hoff = h * 64;
    const int qbase = blockIdx.x * 64;
    const int tid = threadIdx.x;
    const int lane = tid & 63;
    const int wave = tid >> 6;
    const int l15 = lane & 15;
    const int quad = lane >> 4;

    __shared__ unsigned short Vt[64 * VT_STRIDE];  // [d][key] cross 0..95, id 96..127
    __shared__ unsigned short Pl[64 * VT_STRIDE];  // [qrow][key]

    for (int i = tid; i < 96 * 8; i += 256) {
        const int c = i / 96;
        const int key = i - c * 96;
        short8 v = *(const short8*)(Vb + (size_t)(b * 96 + key) * 1280 + hoff + c * 8);
        #pragma unroll
        for (int j = 0; j < 8; ++j)
            Vt[(c * 8 + j) * VT_STRIDE + key] = (unsigned short)v[j];
    }
    {
        const int c = tid >> 5;
        const int key = tid & 31;
        short8 v = *(const short8*)(IVb + (size_t)(b * 32 + key) * 1280 + hoff + c * 8);
        #pragma unroll
        for (int j = 0; j < 8; ++j)
            Vt[(c * 8 + j) * VT_STRIDE + 96 + key] = (unsigned short)v[j];
    }
    __syncthreads();

    const int qrow = b * 4096 + qbase + wave * 16 + l15;
    const unsigned short* qp = Q + (size_t)qrow * 1280 + hoff + quad * 8;
    const short8 aQ0 = *(const short8*)(qp);
    const short8 aQ1 = *(const short8*)(qp + 32);

    const float scale = 0.125f;
    float lC[4] = {0.f, 0.f, 0.f, 0.f};
    float lI[4] = {0.f, 0.f, 0.f, 0.f};

    #pragma unroll
    for (int t = 0; t < 5; ++t) {
        const unsigned short* kp = Kb + (size_t)(b * 96 + t * 16 + l15) * 1280 + hoff + quad * 8;
        const short8 bK0 = *(const short8*)(kp);
        const short8 bK1 = *(const short8*)(kp + 32);
        float4v s = {};
        s = __builtin_amdgcn_mfma_f32_16x16x32_bf16(aQ0, bK0, s, 0, 0, 0);
        s = __builtin_amdgcn_mfma_f32_16x16x32_bf16(aQ1, bK1, s, 0, 0, 0);
        #pragma unroll
        for (int r = 0; r < 4; ++r) {
            float p = __expf(s[r] * scale);
            if (t == 4 && l15 >= 13) p = 0.f;   // keys 77..79 masked
            lC[r] += p;
            Pl[(wave * 16 + quad * 4 + r) * VT_STRIDE + t * 16 + l15] = f2bf(p);
        }
    }
    #pragma unroll
    for (int r = 0; r < 4; ++r)
        Pl[(wave * 16 + quad * 4 + r) * VT_STRIDE + 80 + l15] = 0;

    #pragma unroll
    for (int t = 0; t < 2; ++t) {
        const unsigned short* kp = IKb + (size_t)(b * 32 + t * 16 + l15) * 1280 + hoff + quad * 8;
        const short8 bK0 = *(const short8*)(kp);
        const short8 bK1 = *(const short8*)(kp + 32);
        float4v s = {};
        s = __builtin_amdgcn_mfma_f32_16x16x32_bf16(aQ0, bK0, s, 0, 0, 0);
        s = __builtin_amdgcn_mfma_f32_16x16x32_bf16(aQ1, bK1, s, 0, 0, 0);
        #pragma unroll
        for (int r = 0; r < 4; ++r) {
            const float p = __expf(s[r] * scale);
            lI[r] += p;
            Pl[(wave * 16 + quad * 4 + r) * VT_STRIDE + 96 + t * 16 + l15] = f2bf(p);
        }
    }

    #pragma unroll
    for (int m = 1; m <= 8; m <<= 1) {
        #pragma unroll
        for (int r = 0; r < 4; ++r) {
            lC[r] += __shfl_xor(lC[r], m);
            lI[r] += __shfl_xor(lI[r], m);
        }
    }
    __syncthreads();

    float4v oC[4] = {};
    float4v oI[4] = {};
    #pragma unroll
    for (int kt = 0; kt < 3; ++kt) {
        const short8 aP = *(const short8*)(Pl + (wave * 16 + l15) * VT_STRIDE + kt * 32 + quad * 8);
        #pragma unroll
        for (int td = 0; td < 4; ++td) {
            const short8 bV = *(const short8*)(Vt + (td * 16 + l15) * VT_STRIDE + kt * 32 + quad * 8);
            oC[td] = __builtin_amdgcn_mfma_f32_16x16x32_bf16(aP, bV, oC[td], 0, 0, 0);
        }
    }
    {
        const short8 aP = *(const short8*)(Pl + (wave * 16 + l15) * VT_STRIDE + 96 + quad * 8);
        #pragma unroll
        for (int td = 0; td < 4; ++td) {
            const short8 bV = *(const short8*)(Vt + (td * 16 + l15) * VT_STRIDE + 96 + quad * 8);
            oI[td] = __builtin_amdgcn_mfma_f32_16x16x32_bf16(aP, bV, oI[td], 0, 0, 0);
        }
    }

    float rc[4], ri[4];
    #pragma unroll
    for (int r = 0; r < 4; ++r) { rc[r] = 1.f / lC[r]; ri[r] = 1.f / lI[r]; }

    #pragma unroll
    for (int td = 0; td < 4; ++td) {
        #pragma unroll
        for (int r = 0; r < 4; ++r) {
            const int row = b * 4096 + qbase + wave * 16 + quad * 4 + r;
            const int col = hoff + td * 16 + l15;
            Cmb[(size_t)row * 1280 + col] = f2bf(oC[td][r] * rc[r] + oI[td][r] * ri[r]);
        }
    }
}

// ---------- host launch ----------
extern "C" void kernel_launch(void* const* d_in, const int* in_sizes, int n_in,
                              void* d_out, int out_size, void* d_ws, size_t ws_size,
                              hipStream_t stream) {
    const float* hs  = (const float*)d_in[0];   // [4,4096,1280]
    const float* enc = (const float*)d_in[1];   // [4,77,2048]
    const float* idm = (const float*)d_in[2];   // [4,32,2048]
    const float* Wq  = (const float*)d_in[3];
    const float* Wk  = (const float*)d_in[4];
    const float* Wv  = (const float*)d_in[5];
    const float* Wik = (const float*)d_in[6];
    const float* Wiv = (const float*)d_in[7];
    const float* Wo  = (const float*)d_in[8];
    const float* bo  = (const float*)d_in[9];
    float* out = (float*)d_out;

    char* ws = (char*)d_ws;
    size_t off = 0;
    auto carve = [&](size_t bytes) {
        char* p = ws + off;
        off += (bytes + 255) & ~(size_t)255;
        return p;
    };

    unsigned short* Xh   = (unsigned short*)carve(16384ULL * 1280 * 2); // hs bf16, later 'combined'
    unsigned short* Wq_b = (unsigned short*)carve(1280ULL * 1280 * 2);
    unsigned short* Wk_b = (unsigned short*)carve(1280ULL * 2048 * 2);
    unsigned short* Wv_b = (unsigned short*)carve(1280ULL * 2048 * 2);
    unsigned short* Wik_b= (unsigned short*)carve(1280ULL * 2048 * 2);
    unsigned short* Wiv_b= (unsigned short*)carve(1280ULL * 2048 * 2);
    unsigned short* Wo_b = (unsigned short*)carve(1280ULL * 1280 * 2);
    unsigned short* Encb = (unsigned short*)carve(384ULL * 2048 * 2);  // per-batch padded 96 rows
    unsigned short* Idb  = (unsigned short*)carve(128ULL * 2048 * 2);
    unsigned short* Qb   = (unsigned short*)carve(16384ULL * 1280 * 2);
    unsigned short* Kb   = (unsigned short*)carve(384ULL * 1280 * 2);
    unsigned short* Vb   = (unsigned short*)carve(384ULL * 1280 * 2);
    unsigned short* IKb  = (unsigned short*)carve(128ULL * 1280 * 2);
    unsigned short* IVb  = (unsigned short*)carve(128ULL * 1280 * 2);
    (void)ws_size; (void)in_sizes; (void)n_in; (void)out_size;

    cast_bf16_kernel<<<(4 * 4096 * 1280 / 4 + 255) / 256, 256, 0, stream>>>(
        hs, Xh, 4 * 4096 * 1280);
    cast_enc_pad_kernel<<<(4 * 77 * 2048 / 4 + 255) / 256, 256, 0, stream>>>(enc, Encb);

    CastBatch cb;
    cb.src[0] = Wq;  cb.dst[0] = Wq_b;  cb.n[0] = 1280 * 1280;
    cb.src[1] = Wk;  cb.dst[1] = Wk_b;  cb.n[1] = 1280 * 2048;
    cb.src[2] = Wv;  cb.dst[2] = Wv_b;  cb.n[2] = 1280 * 2048;
    cb.src[3] = Wik; cb.dst[3] = Wik_b; cb.n[3] = 1280 * 2048;
    cb.src[4] = Wiv; cb.dst[4] = Wiv_b; cb.n[4] = 1280 * 2048;
    cb.src[5] = Wo;  cb.dst[5] = Wo_b;  cb.n[5] = 1280 * 1280;
    cb.src[6] = idm; cb.dst[6] = Idb;   cb.n[6] = 4 * 32 * 2048;
    cb.src[7] = nullptr; cb.dst[7] = nullptr; cb.n[7] = 0;
    cast_batch_kernel<<<dim3((1280 * 2048 / 4 + 255) / 256, 7), 256, 0, stream>>>(cb);

    // Q = hs @ Wq^T -> bf16
    gemm_bt_kernel<1><<<dim3(128, 10), 256, 0, stream>>>(
        Xh, Wq_b, nullptr, Qb, nullptr, nullptr, 16384, 1280, 1280);

    // K/V/iK/iV projections -> bf16 (z=0..3)
    gemm_kv4_kernel<<<dim3(3, 10, 4), 256, 0, stream>>>(
        Encb, Idb, Wk_b, Wv_b, Wik_b, Wiv_b, Kb, Vb, IKb, IVb, 1280, 2048);

    // fused MFMA attention -> combined (reuses Xh)
    attn_mfma_kernel<<<dim3(64, 20, 4), 256, 0, stream>>>(Qb, Kb, Vb, IKb, IVb, Xh);

    // out = combined @ Wo^T + bo + residual
    gemm_bt_kernel<2><<<dim3(128, 10), 256, 0, stream>>>(
        Xh, Wo_b, out, nullptr, bo, hs, 16384, 1280, 1280);
}